// Round 5
// baseline (174.908 us; speedup 1.0000x reference)
//
#include <hip/hip_runtime.h>
#include <hip/hip_bf16.h>

// Triangle attention (start) — N=256, C=128, H=4, D=32, f16 MFMA pipeline.
// R4: j-split mega kernel (2 blocks per i -> 2 blocks/CU), odd-word LDS strides
// (scr 98, Ksm 34) to kill bank aliasing. K/V recomputed per block.

typedef _Float16 half8 __attribute__((ext_vector_type(8)));
typedef _Float16 half4 __attribute__((ext_vector_type(4)));
typedef float floatx4 __attribute__((ext_vector_type(4)));

#define NN 256
#define CC 128
#define HH 4
#define DD 32
#define NR (NN*NN)
#define LN_EPS 1e-5f
#define MFMA(a,b,c) __builtin_amdgcn_mfma_f32_16x16x32_f16(a,b,c,0,0,0)
#define ZERO4 ((floatx4)(0.f))
#define KSTR 34      // Ksm row stride (halves): 17 words, odd -> conflict-free spread
#define SSTR 98      // scr row stride (halves): 49 words, odd

__device__ inline half4 cvt4(floatx4 v) {
    half4 r; r[0]=(_Float16)v[0]; r[1]=(_Float16)v[1];
    r[2]=(_Float16)v[2]; r[3]=(_Float16)v[3]; return r;
}

// ---------------- Stage 1: weight prep ----------------
__global__ __launch_bounds__(256) void prep_weights(
    const float* __restrict__ Wq, const float* __restrict__ Wk,
    const float* __restrict__ Wv, const float* __restrict__ Wg,
    const float* __restrict__ Wo, const float* __restrict__ Wb,
    _Float16* __restrict__ WqT, _Float16* __restrict__ WkT,
    _Float16* __restrict__ WvT, _Float16* __restrict__ WgT,
    _Float16* __restrict__ WoT, _Float16* __restrict__ WbT)
{
    int id = blockIdx.x * 256 + threadIdx.x;
    if (id < 5 * 16384) {
        int m = id / 16384, e = id % 16384;
        int n = e >> 7, c = e & 127;
        const float* src = (m==0)?Wq:(m==1)?Wk:(m==2)?Wv:(m==3)?Wg:Wo;
        _Float16* dst    = (m==0)?WqT:(m==1)?WkT:(m==2)?WvT:(m==3)?WgT:WoT;
        dst[n*128 + c] = (_Float16)src[c*128 + n];
    } else {
        int e = id - 5*16384;   // WbT padded to [16][128]
        if (e < 16*128) {
            int n = e >> 7, c = e & 127;
            WbT[n*128 + c] = (n < HH) ? (_Float16)Wb[c*HH + n] : (_Float16)0.f;
        }
    }
}

// ---------------- Stage 2: LN -> zh (f16) + pair bias ----------------
__global__ __launch_bounds__(256) void bias_ln_kernel(
    const float* __restrict__ pair, const float* __restrict__ ln_scale,
    const float* __restrict__ ln_bias, const _Float16* __restrict__ WbT,
    _Float16* __restrict__ zh, float* __restrict__ biasF)
{
    int wave = threadIdx.x >> 6, lane = threadIdx.x & 63;
    int mtile = blockIdx.x * 4 + wave;
    int lr = lane & 15, lg = lane >> 4;
    size_t row = (size_t)mtile*16 + lr;

    float xv[4][8];
    float s = 0.f, ss = 0.f;
    #pragma unroll
    for (int ks = 0; ks < 4; ++ks) {
        const float* pr = &pair[row*CC + ks*32 + lg*8];
        float4 a = *(const float4*)pr;
        float4 b = *(const float4*)(pr + 4);
        xv[ks][0]=a.x; xv[ks][1]=a.y; xv[ks][2]=a.z; xv[ks][3]=a.w;
        xv[ks][4]=b.x; xv[ks][5]=b.y; xv[ks][6]=b.z; xv[ks][7]=b.w;
        s  += a.x+a.y+a.z+a.w + b.x+b.y+b.z+b.w;
        ss += a.x*a.x+a.y*a.y+a.z*a.z+a.w*a.w + b.x*b.x+b.y*b.y+b.z*b.z+b.w*b.w;
    }
    s  += __shfl_xor(s, 16);  s  += __shfl_xor(s, 32);
    ss += __shfl_xor(ss, 16); ss += __shfl_xor(ss, 32);
    float mu   = s * (1.f/128.f);
    float var  = ss * (1.f/128.f) - mu*mu;
    float rstd = rsqrtf(var + LN_EPS);

    half8 zfrag[4];
    #pragma unroll
    for (int ks = 0; ks < 4; ++ks) {
        const float* sc = &ln_scale[ks*32 + lg*8];
        const float* bi = &ln_bias[ks*32 + lg*8];
        #pragma unroll
        for (int e = 0; e < 8; ++e)
            zfrag[ks][e] = (_Float16)((xv[ks][e] - mu) * rstd * sc[e] + bi[e]);
        *(half8*)&zh[row*CC + ks*32 + lg*8] = zfrag[ks];
    }

    // bias = z @ Wb  (swapped: lane -> zrow=lr, h = lg*4+r; lg==0 holds h=0..3)
    floatx4 acc2 = ZERO4;
    #pragma unroll
    for (int ks = 0; ks < 4; ++ks) {
        half8 w = *(const half8*)&WbT[lr*128 + ks*32 + lg*8];
        acc2 = MFMA(w, zfrag[ks], acc2);
    }
    if (lg == 0) {
        #pragma unroll
        for (int r = 0; r < 4; ++r)
            biasF[(size_t)r*NR + row] = acc2[r];   // biasF[h][j*256+k]
    }
}

// ---------------- Stage 3: fused per-(i, j-half) mega kernel ----------------
__global__ __launch_bounds__(512, 4) void mega_kernel(
    const _Float16* __restrict__ zh,
    const _Float16* __restrict__ WqT, const _Float16* __restrict__ WkT,
    const _Float16* __restrict__ WvT, const _Float16* __restrict__ WgT,
    const _Float16* __restrict__ WoT,
    const float* __restrict__ bg, const float* __restrict__ biasF,
    const float* __restrict__ bo, float* __restrict__ out)
{
    __shared__ _Float16 Ksm[256*KSTR];   // [k][d], odd-word row stride
    __shared__ _Float16 Vt[32*264];      // [d][k], row pad 256->264
    __shared__ _Float16 scr[8*16*SSTR];  // per-wave layout-transform scratch

    const int tid  = threadIdx.x;
    const int wave = tid >> 6, lane = tid & 63;
    const int lr   = lane & 15, lg = lane >> 4;
    const int ib   = blockIdx.x >> 1;            // pair row i
    const int jh   = blockIdx.x & 1;             // j half
    const int jbase = jh*128 + wave*16;          // this wave's 16 j-rows (local)
    const int kbase = wave*32;                   // this wave's 32 k-rows for K/V
    const size_t rb = (size_t)ib * NN;
    const int sbase = wave*(16*SSTR) + lr*SSTR;  // scratch row for lane

    // ---- z fragments for own j rows: [zrow=lr][c=lg*8+e] ----
    half8 zfj[4];
    #pragma unroll
    for (int ks = 0; ks < 4; ++ks)
        zfj[ks] = *(const half8*)&zh[(rb + jbase + lr)*CC + ks*32 + lg*8];

    half8 ofrag[4];   // [h] gated attention output fragments

    #pragma unroll
    for (int h = 0; h < HH; ++h) {
        // ---- Q_h (swapped: A=WqT, B=zfj -> lane: j=lr, d=lg*4+r per ntl) ----
        floatx4 qa0 = ZERO4, qa1 = ZERO4;
        #pragma unroll
        for (int ks = 0; ks < 4; ++ks) {
            qa0 = MFMA(*(const half8*)&WqT[((2*h+0)*16 + lr)*CC + ks*32 + lg*8], zfj[ks], qa0);
            qa1 = MFMA(*(const half8*)&WqT[((2*h+1)*16 + lr)*CC + ks*32 + lg*8], zfj[ks], qa1);
        }
        qa0 *= 0.17677669529663687f;   // 1/sqrt(32)
        qa1 *= 0.17677669529663687f;
        *(half4*)&scr[sbase + lg*4]      = cvt4(qa0);
        *(half4*)&scr[sbase + 16 + lg*4] = cvt4(qa1);
        half8 qf = *(const half8*)&scr[sbase + lg*8];   // [j=lr][d=lg*8+e]

        // ---- gate_h (stays in acc layout: d = ntl*16 + lg*4 + r) ----
        floatx4 ga0 = ZERO4, ga1 = ZERO4;
        #pragma unroll
        for (int ks = 0; ks < 4; ++ks) {
            ga0 = MFMA(*(const half8*)&WgT[((2*h+0)*16 + lr)*CC + ks*32 + lg*8], zfj[ks], ga0);
            ga1 = MFMA(*(const half8*)&WgT[((2*h+1)*16 + lr)*CC + ks*32 + lg*8], zfj[ks], ga1);
        }
        floatx4 bg0 = *(const floatx4*)&bg[(2*h+0)*16 + lg*4];
        floatx4 bg1 = *(const floatx4*)&bg[(2*h+1)*16 + lg*4];
        half4 gt0, gt1;
        #pragma unroll
        for (int r = 0; r < 4; ++r) {
            gt0[r] = (_Float16)(1.f/(1.f + __expf(-(ga0[r] + bg0[r]))));
            gt1[r] = (_Float16)(1.f/(1.f + __expf(-(ga1[r] + bg1[r]))));
        }

        __syncthreads();   // previous head's readers done with Ksm/Vt

        // ---- K_h/V_h for this wave's 32 k-rows ----
        #pragma unroll
        for (int at = 0; at < 2; ++at) {
            half8 zk[4];
            #pragma unroll
            for (int ks = 0; ks < 4; ++ks)
                zk[ks] = *(const half8*)&zh[(rb + kbase + at*16 + lr)*CC + ks*32 + lg*8];
            floatx4 ak0 = ZERO4, ak1 = ZERO4, av0 = ZERO4, av1 = ZERO4;
            #pragma unroll
            for (int ks = 0; ks < 4; ++ks) {
                ak0 = MFMA(*(const half8*)&WkT[((2*h+0)*16 + lr)*CC + ks*32 + lg*8], zk[ks], ak0);
                ak1 = MFMA(*(const half8*)&WkT[((2*h+1)*16 + lr)*CC + ks*32 + lg*8], zk[ks], ak1);
                av0 = MFMA(zk[ks], *(const half8*)&WvT[((2*h+0)*16 + lr)*CC + ks*32 + lg*8], av0);
                av1 = MFMA(zk[ks], *(const half8*)&WvT[((2*h+1)*16 + lr)*CC + ks*32 + lg*8], av1);
            }
            // K: lane k = kbase+at*16+lr, d = ntl*16 + lg*4 + r
            int kk = kbase + at*16 + lr;
            *(half4*)&Ksm[kk*KSTR + lg*4]      = cvt4(ak0);
            *(half4*)&Ksm[kk*KSTR + 16 + lg*4] = cvt4(ak1);
            // V: lane d = ntl*16+lr, k = kbase+at*16+lg*4 .. +3
            int k0 = kbase + at*16 + lg*4;
            *(half4*)&Vt[lr*264 + k0]        = cvt4(av0);
            *(half4*)&Vt[(16 + lr)*264 + k0] = cvt4(av1);
        }

        __syncthreads();   // K/V visible to all waves

        // ---- S = K·Q^T (swapped): lane: j = jbase+lr, k = nt*16+lg*4+r ----
        int j = jbase + lr;
        floatx4 sacc[16];
        #pragma unroll
        for (int nt = 0; nt < 16; ++nt) {
            half8 kf = *(const half8*)&Ksm[(nt*16 + lr)*KSTR + lg*8];
            floatx4 a = MFMA(kf, qf, ZERO4);
            a += *(const floatx4*)&biasF[((size_t)h*NN + j)*NN + nt*16 + lg*4];
            sacc[nt] = a;
        }
        // ---- softmax over k (row spread across 4 lg-lanes) ----
        float m = -1e30f;
        #pragma unroll
        for (int nt = 0; nt < 16; ++nt)
            #pragma unroll
            for (int r = 0; r < 4; ++r) m = fmaxf(m, sacc[nt][r]);
        m = fmaxf(m, __shfl_xor(m, 16));
        m = fmaxf(m, __shfl_xor(m, 32));
        float l = 0.f;
        #pragma unroll
        for (int nt = 0; nt < 16; ++nt)
            #pragma unroll
            for (int r = 0; r < 4; ++r) {
                float p = __expf(sacc[nt][r] - m);
                sacc[nt][r] = p; l += p;
            }
        l += __shfl_xor(l, 16);
        l += __shfl_xor(l, 32);
        float linv = 1.f / l;

        // ---- PV: per 32-k group, P->f16 frag via scr, A=Vt rows ----
        floatx4 oacc0 = ZERO4, oacc1 = ZERO4;
        #pragma unroll
        for (int g = 0; g < 8; ++g) {
            int sb = sbase + (g&1)*48;
            *(half4*)&scr[sb + lg*4]      = cvt4(sacc[2*g]);
            *(half4*)&scr[sb + 16 + lg*4] = cvt4(sacc[2*g+1]);
            half8 pf  = *(const half8*)&scr[sb + lg*8];        // [j=lr][k=g*32+lg*8+e]
            half8 vf0 = *(const half8*)&Vt[lr*264        + g*32 + lg*8];
            half8 vf1 = *(const half8*)&Vt[(16+lr)*264   + g*32 + lg*8];
            oacc0 = MFMA(vf0, pf, oacc0);
            oacc1 = MFMA(vf1, pf, oacc1);
        }
        // ---- normalize, gate, pack -> ofrag[h] (d layout = lg*4+r) ----
        half4 pk0, pk1;
        #pragma unroll
        for (int r = 0; r < 4; ++r) {
            pk0[r] = (_Float16)(oacc0[r] * linv * (float)gt0[r]);
            pk1[r] = (_Float16)(oacc1[r] * linv * (float)gt1[r]);
        }
        *(half4*)&scr[sbase + lg*4]      = pk0;
        *(half4*)&scr[sbase + 16 + lg*4] = pk1;
        ofrag[h] = *(const half8*)&scr[sbase + lg*8];  // [j=lr][c=h*32+lg*8+e]
    }

    // ---- out projection: A=WoT, B=ofrag -> lane: j=lr, 4 consecutive cols ----
    size_t orow = rb + jbase + lr;
    #pragma unroll
    for (int nt = 0; nt < 8; ++nt) {
        floatx4 a = ZERO4;
        #pragma unroll
        for (int ks = 0; ks < 4; ++ks)
            a = MFMA(*(const half8*)&WoT[(nt*16 + lr)*CC + ks*32 + lg*8],
                     ofrag[ks], a);
        int col = nt*16 + lg*4;
        a += *(const floatx4*)&bo[col];
        *(floatx4*)&out[orow*CC + col] = a;
    }
}

// ---------------- launch ----------------
extern "C" void kernel_launch(void* const* d_in, const int* in_sizes, int n_in,
                              void* d_out, int out_size, void* d_ws, size_t ws_size,
                              hipStream_t stream)
{
    const float* pair     = (const float*)d_in[0];
    const float* ln_scale = (const float*)d_in[1];
    const float* ln_bias  = (const float*)d_in[2];
    const float* Wq       = (const float*)d_in[3];
    const float* Wk       = (const float*)d_in[4];
    const float* Wv       = (const float*)d_in[5];
    const float* Wb       = (const float*)d_in[6];
    const float* Wg       = (const float*)d_in[7];
    const float* bg       = (const float*)d_in[8];
    const float* Wo       = (const float*)d_in[9];
    const float* bo       = (const float*)d_in[10];
    float* out = (float*)d_out;

    char* ws = (char*)d_ws;
    _Float16* zh  = (_Float16*)ws; ws += (size_t)NR * CC * sizeof(_Float16); // 16.78 MB
    float* biasF  = (float*)ws;    ws += (size_t)HH * NR * sizeof(float);    // 1 MB
    _Float16* WqT = (_Float16*)ws; ws += 128*128*sizeof(_Float16);
    _Float16* WkT = (_Float16*)ws; ws += 128*128*sizeof(_Float16);
    _Float16* WvT = (_Float16*)ws; ws += 128*128*sizeof(_Float16);
    _Float16* WgT = (_Float16*)ws; ws += 128*128*sizeof(_Float16);
    _Float16* WoT = (_Float16*)ws; ws += 128*128*sizeof(_Float16);
    _Float16* WbT = (_Float16*)ws; ws += 16*128*sizeof(_Float16);

    prep_weights<<<(5*16384 + 16*128 + 255)/256, 256, 0, stream>>>(
        Wq, Wk, Wv, Wg, Wo, Wb, WqT, WkT, WvT, WgT, WoT, WbT);

    bias_ln_kernel<<<NR/16/4, 256, 0, stream>>>(
        pair, ln_scale, ln_bias, WbT, zh, biasF);

    mega_kernel<<<2*NN, 512, 0, stream>>>(
        zh, WqT, WkT, WvT, WgT, WoT, bg, biasF, bo, out);
}

// Round 6
// 157.849 us; speedup vs baseline: 1.1081x; 1.1081x over previous
//
#include <hip/hip_runtime.h>
#include <hip/hip_bf16.h>

// Triangle attention (start) — N=256, C=128, H=4, D=32, f16 MFMA pipeline.
// R5: R4's j-split mega kernel (grid=512, 2 blocks/CU) with corrected
// __launch_bounds__(512,2) — R4's (512,4) capped VGPR at 64 and spilled.

typedef _Float16 half8 __attribute__((ext_vector_type(8)));
typedef _Float16 half4 __attribute__((ext_vector_type(4)));
typedef float floatx4 __attribute__((ext_vector_type(4)));

#define NN 256
#define CC 128
#define HH 4
#define DD 32
#define NR (NN*NN)
#define LN_EPS 1e-5f
#define MFMA(a,b,c) __builtin_amdgcn_mfma_f32_16x16x32_f16(a,b,c,0,0,0)
#define ZERO4 ((floatx4)(0.f))
#define KSTR 34      // Ksm row stride (halves): 17 words, odd -> conflict-free spread
#define SSTR 98      // scr row stride (halves): 49 words, odd

__device__ inline half4 cvt4(floatx4 v) {
    half4 r; r[0]=(_Float16)v[0]; r[1]=(_Float16)v[1];
    r[2]=(_Float16)v[2]; r[3]=(_Float16)v[3]; return r;
}

// ---------------- Stage 1: weight prep ----------------
__global__ __launch_bounds__(256) void prep_weights(
    const float* __restrict__ Wq, const float* __restrict__ Wk,
    const float* __restrict__ Wv, const float* __restrict__ Wg,
    const float* __restrict__ Wo, const float* __restrict__ Wb,
    _Float16* __restrict__ WqT, _Float16* __restrict__ WkT,
    _Float16* __restrict__ WvT, _Float16* __restrict__ WgT,
    _Float16* __restrict__ WoT, _Float16* __restrict__ WbT)
{
    int id = blockIdx.x * 256 + threadIdx.x;
    if (id < 5 * 16384) {
        int m = id / 16384, e = id % 16384;
        int n = e >> 7, c = e & 127;
        const float* src = (m==0)?Wq:(m==1)?Wk:(m==2)?Wv:(m==3)?Wg:Wo;
        _Float16* dst    = (m==0)?WqT:(m==1)?WkT:(m==2)?WvT:(m==3)?WgT:WoT;
        dst[n*128 + c] = (_Float16)src[c*128 + n];
    } else {
        int e = id - 5*16384;   // WbT padded to [16][128]
        if (e < 16*128) {
            int n = e >> 7, c = e & 127;
            WbT[n*128 + c] = (n < HH) ? (_Float16)Wb[c*HH + n] : (_Float16)0.f;
        }
    }
}

// ---------------- Stage 2: LN -> zh (f16) + pair bias ----------------
__global__ __launch_bounds__(256) void bias_ln_kernel(
    const float* __restrict__ pair, const float* __restrict__ ln_scale,
    const float* __restrict__ ln_bias, const _Float16* __restrict__ WbT,
    _Float16* __restrict__ zh, float* __restrict__ biasF)
{
    int wave = threadIdx.x >> 6, lane = threadIdx.x & 63;
    int mtile = blockIdx.x * 4 + wave;
    int lr = lane & 15, lg = lane >> 4;
    size_t row = (size_t)mtile*16 + lr;

    float xv[4][8];
    float s = 0.f, ss = 0.f;
    #pragma unroll
    for (int ks = 0; ks < 4; ++ks) {
        const float* pr = &pair[row*CC + ks*32 + lg*8];
        float4 a = *(const float4*)pr;
        float4 b = *(const float4*)(pr + 4);
        xv[ks][0]=a.x; xv[ks][1]=a.y; xv[ks][2]=a.z; xv[ks][3]=a.w;
        xv[ks][4]=b.x; xv[ks][5]=b.y; xv[ks][6]=b.z; xv[ks][7]=b.w;
        s  += a.x+a.y+a.z+a.w + b.x+b.y+b.z+b.w;
        ss += a.x*a.x+a.y*a.y+a.z*a.z+a.w*a.w + b.x*b.x+b.y*b.y+b.z*b.z+b.w*b.w;
    }
    s  += __shfl_xor(s, 16);  s  += __shfl_xor(s, 32);
    ss += __shfl_xor(ss, 16); ss += __shfl_xor(ss, 32);
    float mu   = s * (1.f/128.f);
    float var  = ss * (1.f/128.f) - mu*mu;
    float rstd = rsqrtf(var + LN_EPS);

    half8 zfrag[4];
    #pragma unroll
    for (int ks = 0; ks < 4; ++ks) {
        const float* sc = &ln_scale[ks*32 + lg*8];
        const float* bi = &ln_bias[ks*32 + lg*8];
        #pragma unroll
        for (int e = 0; e < 8; ++e)
            zfrag[ks][e] = (_Float16)((xv[ks][e] - mu) * rstd * sc[e] + bi[e]);
        *(half8*)&zh[row*CC + ks*32 + lg*8] = zfrag[ks];
    }

    // bias = z @ Wb  (swapped: lane -> zrow=lr, h = lg*4+r; lg==0 holds h=0..3)
    floatx4 acc2 = ZERO4;
    #pragma unroll
    for (int ks = 0; ks < 4; ++ks) {
        half8 w = *(const half8*)&WbT[lr*128 + ks*32 + lg*8];
        acc2 = MFMA(w, zfrag[ks], acc2);
    }
    if (lg == 0) {
        #pragma unroll
        for (int r = 0; r < 4; ++r)
            biasF[(size_t)r*NR + row] = acc2[r];   // biasF[h][j*256+k]
    }
}

// ---------------- Stage 3: fused per-(i, j-half) mega kernel ----------------
__global__ __launch_bounds__(512, 2) void mega_kernel(
    const _Float16* __restrict__ zh,
    const _Float16* __restrict__ WqT, const _Float16* __restrict__ WkT,
    const _Float16* __restrict__ WvT, const _Float16* __restrict__ WgT,
    const _Float16* __restrict__ WoT,
    const float* __restrict__ bg, const float* __restrict__ biasF,
    const float* __restrict__ bo, float* __restrict__ out)
{
    __shared__ _Float16 Ksm[256*KSTR];   // [k][d], odd-word row stride
    __shared__ _Float16 Vt[32*264];      // [d][k], row pad 256->264
    __shared__ _Float16 scr[8*16*SSTR];  // per-wave layout-transform scratch

    const int tid  = threadIdx.x;
    const int wave = tid >> 6, lane = tid & 63;
    const int lr   = lane & 15, lg = lane >> 4;
    const int ib   = blockIdx.x >> 1;            // pair row i
    const int jh   = blockIdx.x & 1;             // j half
    const int jbase = jh*128 + wave*16;          // this wave's 16 j-rows (local)
    const int kbase = wave*32;                   // this wave's 32 k-rows for K/V
    const size_t rb = (size_t)ib * NN;
    const int sbase = wave*(16*SSTR) + lr*SSTR;  // scratch row for lane

    // ---- z fragments for own j rows: [zrow=lr][c=lg*8+e] ----
    half8 zfj[4];
    #pragma unroll
    for (int ks = 0; ks < 4; ++ks)
        zfj[ks] = *(const half8*)&zh[(rb + jbase + lr)*CC + ks*32 + lg*8];

    half8 ofrag[4];   // [h] gated attention output fragments

    #pragma unroll
    for (int h = 0; h < HH; ++h) {
        // ---- Q_h (swapped: A=WqT, B=zfj -> lane: j=lr, d=lg*4+r per ntl) ----
        floatx4 qa0 = ZERO4, qa1 = ZERO4;
        #pragma unroll
        for (int ks = 0; ks < 4; ++ks) {
            qa0 = MFMA(*(const half8*)&WqT[((2*h+0)*16 + lr)*CC + ks*32 + lg*8], zfj[ks], qa0);
            qa1 = MFMA(*(const half8*)&WqT[((2*h+1)*16 + lr)*CC + ks*32 + lg*8], zfj[ks], qa1);
        }
        qa0 *= 0.17677669529663687f;   // 1/sqrt(32)
        qa1 *= 0.17677669529663687f;
        *(half4*)&scr[sbase + lg*4]      = cvt4(qa0);
        *(half4*)&scr[sbase + 16 + lg*4] = cvt4(qa1);
        half8 qf = *(const half8*)&scr[sbase + lg*8];   // [j=lr][d=lg*8+e]

        // ---- gate_h (stays in acc layout: d = ntl*16 + lg*4 + r) ----
        floatx4 ga0 = ZERO4, ga1 = ZERO4;
        #pragma unroll
        for (int ks = 0; ks < 4; ++ks) {
            ga0 = MFMA(*(const half8*)&WgT[((2*h+0)*16 + lr)*CC + ks*32 + lg*8], zfj[ks], ga0);
            ga1 = MFMA(*(const half8*)&WgT[((2*h+1)*16 + lr)*CC + ks*32 + lg*8], zfj[ks], ga1);
        }
        floatx4 bg0 = *(const floatx4*)&bg[(2*h+0)*16 + lg*4];
        floatx4 bg1 = *(const floatx4*)&bg[(2*h+1)*16 + lg*4];
        half4 gt0, gt1;
        #pragma unroll
        for (int r = 0; r < 4; ++r) {
            gt0[r] = (_Float16)(1.f/(1.f + __expf(-(ga0[r] + bg0[r]))));
            gt1[r] = (_Float16)(1.f/(1.f + __expf(-(ga1[r] + bg1[r]))));
        }

        __syncthreads();   // previous head's readers done with Ksm/Vt

        // ---- K_h/V_h for this wave's 32 k-rows ----
        #pragma unroll
        for (int at = 0; at < 2; ++at) {
            half8 zk[4];
            #pragma unroll
            for (int ks = 0; ks < 4; ++ks)
                zk[ks] = *(const half8*)&zh[(rb + kbase + at*16 + lr)*CC + ks*32 + lg*8];
            floatx4 ak0 = ZERO4, ak1 = ZERO4, av0 = ZERO4, av1 = ZERO4;
            #pragma unroll
            for (int ks = 0; ks < 4; ++ks) {
                ak0 = MFMA(*(const half8*)&WkT[((2*h+0)*16 + lr)*CC + ks*32 + lg*8], zk[ks], ak0);
                ak1 = MFMA(*(const half8*)&WkT[((2*h+1)*16 + lr)*CC + ks*32 + lg*8], zk[ks], ak1);
                av0 = MFMA(zk[ks], *(const half8*)&WvT[((2*h+0)*16 + lr)*CC + ks*32 + lg*8], av0);
                av1 = MFMA(zk[ks], *(const half8*)&WvT[((2*h+1)*16 + lr)*CC + ks*32 + lg*8], av1);
            }
            // K: lane k = kbase+at*16+lr, d = ntl*16 + lg*4 + r
            int kk = kbase + at*16 + lr;
            *(half4*)&Ksm[kk*KSTR + lg*4]      = cvt4(ak0);
            *(half4*)&Ksm[kk*KSTR + 16 + lg*4] = cvt4(ak1);
            // V: lane d = ntl*16+lr, k = kbase+at*16+lg*4 .. +3
            int k0 = kbase + at*16 + lg*4;
            *(half4*)&Vt[lr*264 + k0]        = cvt4(av0);
            *(half4*)&Vt[(16 + lr)*264 + k0] = cvt4(av1);
        }

        __syncthreads();   // K/V visible to all waves

        // ---- S = K·Q^T (swapped): lane: j = jbase+lr, k = nt*16+lg*4+r ----
        int j = jbase + lr;
        floatx4 sacc[16];
        #pragma unroll
        for (int nt = 0; nt < 16; ++nt) {
            half8 kf = *(const half8*)&Ksm[(nt*16 + lr)*KSTR + lg*8];
            floatx4 a = MFMA(kf, qf, ZERO4);
            a += *(const floatx4*)&biasF[((size_t)h*NN + j)*NN + nt*16 + lg*4];
            sacc[nt] = a;
        }
        // ---- softmax over k (row spread across 4 lg-lanes) ----
        float m = -1e30f;
        #pragma unroll
        for (int nt = 0; nt < 16; ++nt)
            #pragma unroll
            for (int r = 0; r < 4; ++r) m = fmaxf(m, sacc[nt][r]);
        m = fmaxf(m, __shfl_xor(m, 16));
        m = fmaxf(m, __shfl_xor(m, 32));
        float l = 0.f;
        #pragma unroll
        for (int nt = 0; nt < 16; ++nt)
            #pragma unroll
            for (int r = 0; r < 4; ++r) {
                float p = __expf(sacc[nt][r] - m);
                sacc[nt][r] = p; l += p;
            }
        l += __shfl_xor(l, 16);
        l += __shfl_xor(l, 32);
        float linv = 1.f / l;

        // ---- PV: per 32-k group, P->f16 frag via scr, A=Vt rows ----
        floatx4 oacc0 = ZERO4, oacc1 = ZERO4;
        #pragma unroll
        for (int g = 0; g < 8; ++g) {
            int sb = sbase + (g&1)*48;
            *(half4*)&scr[sb + lg*4]      = cvt4(sacc[2*g]);
            *(half4*)&scr[sb + 16 + lg*4] = cvt4(sacc[2*g+1]);
            half8 pf  = *(const half8*)&scr[sb + lg*8];        // [j=lr][k=g*32+lg*8+e]
            half8 vf0 = *(const half8*)&Vt[lr*264        + g*32 + lg*8];
            half8 vf1 = *(const half8*)&Vt[(16+lr)*264   + g*32 + lg*8];
            oacc0 = MFMA(vf0, pf, oacc0);
            oacc1 = MFMA(vf1, pf, oacc1);
        }
        // ---- normalize, gate, pack -> ofrag[h] (d layout = lg*4+r) ----
        half4 pk0, pk1;
        #pragma unroll
        for (int r = 0; r < 4; ++r) {
            pk0[r] = (_Float16)(oacc0[r] * linv * (float)gt0[r]);
            pk1[r] = (_Float16)(oacc1[r] * linv * (float)gt1[r]);
        }
        *(half4*)&scr[sbase + lg*4]      = pk0;
        *(half4*)&scr[sbase + 16 + lg*4] = pk1;
        ofrag[h] = *(const half8*)&scr[sbase + lg*8];  // [j=lr][c=h*32+lg*8+e]
    }

    // ---- out projection: A=WoT, B=ofrag -> lane: j=lr, 4 consecutive cols ----
    size_t orow = rb + jbase + lr;
    #pragma unroll
    for (int nt = 0; nt < 8; ++nt) {
        floatx4 a = ZERO4;
        #pragma unroll
        for (int ks = 0; ks < 4; ++ks)
            a = MFMA(*(const half8*)&WoT[(nt*16 + lr)*CC + ks*32 + lg*8],
                     ofrag[ks], a);
        int col = nt*16 + lg*4;
        a += *(const floatx4*)&bo[col];
        *(floatx4*)&out[orow*CC + col] = a;
    }
}

// ---------------- launch ----------------
extern "C" void kernel_launch(void* const* d_in, const int* in_sizes, int n_in,
                              void* d_out, int out_size, void* d_ws, size_t ws_size,
                              hipStream_t stream)
{
    const float* pair     = (const float*)d_in[0];
    const float* ln_scale = (const float*)d_in[1];
    const float* ln_bias  = (const float*)d_in[2];
    const float* Wq       = (const float*)d_in[3];
    const float* Wk       = (const float*)d_in[4];
    const float* Wv       = (const float*)d_in[5];
    const float* Wb       = (const float*)d_in[6];
    const float* Wg       = (const float*)d_in[7];
    const float* bg       = (const float*)d_in[8];
    const float* Wo       = (const float*)d_in[9];
    const float* bo       = (const float*)d_in[10];
    float* out = (float*)d_out;

    char* ws = (char*)d_ws;
    _Float16* zh  = (_Float16*)ws; ws += (size_t)NR * CC * sizeof(_Float16); // 16.78 MB
    float* biasF  = (float*)ws;    ws += (size_t)HH * NR * sizeof(float);    // 1 MB
    _Float16* WqT = (_Float16*)ws; ws += 128*128*sizeof(_Float16);
    _Float16* WkT = (_Float16*)ws; ws += 128*128*sizeof(_Float16);
    _Float16* WvT = (_Float16*)ws; ws += 128*128*sizeof(_Float16);
    _Float16* WgT = (_Float16*)ws; ws += 128*128*sizeof(_Float16);
    _Float16* WoT = (_Float16*)ws; ws += 128*128*sizeof(_Float16);
    _Float16* WbT = (_Float16*)ws; ws += 16*128*sizeof(_Float16);

    prep_weights<<<(5*16384 + 16*128 + 255)/256, 256, 0, stream>>>(
        Wq, Wk, Wv, Wg, Wo, Wb, WqT, WkT, WvT, WgT, WoT, WbT);

    bias_ln_kernel<<<NR/16/4, 256, 0, stream>>>(
        pair, ln_scale, ln_bias, WbT, zh, biasF);

    mega_kernel<<<2*NN, 512, 0, stream>>>(
        zh, WqT, WkT, WvT, WgT, WoT, bg, biasF, bo, out);
}